// Round 1
// 714.202 us; speedup vs baseline: 1.0162x; 1.0162x over previous
//
#include <hip/hip_runtime.h>
#include <math.h>

#define NF 12
#define NC 27
#define KD 5
#define T_IN 65536
#define T_OUT 65532
#define CHUNKS 4
#define TILE 4096   // 256 threads * 4 outputs * 4 chunks

// Build one filter's 3 effective taps.
// Window at n = 1.25*k is {~1e-8, 0.34, 1.0, 0.34, ~1e-8}: taps k=0,4 carry
// |w| ~ 1e-8 and are dropped (adds <= ~1e-6 abs error vs reference; tolerance
// slack is ~1.5e-2).
__device__ __forceinline__ float4 make_taps(float lo_in, float band_in)
{
    const float PI = 3.14159265358979323846f;
    float lo = fabsf(lo_in) + 0.01f;              // MIN_FREQ / FS
    float hi = lo + fabsf(band_in);

    float bp[KD];
    bp[2] = 2.0f * hi - 2.0f * lo;                // sinc(0) = 1 center tap
    #pragma unroll
    for (int j = 1; j <= 2; ++j) {
        // arg = 2*pi*FS*freq*(j/FS) = 2*pi*freq*j
        float ah = 2.0f * PI * hi * (float)j;
        float al = 2.0f * PI * lo * (float)j;
        float v = 2.0f * hi * (sinf(ah) / ah) - 2.0f * lo * (sinf(al) / al);
        bp[2 + j] = v;
        bp[2 - j] = v;
    }
    float mx = bp[0];
    #pragma unroll
    for (int k = 1; k < KD; ++k) mx = fmaxf(mx, bp[k]);

    float w[3];
    #pragma unroll
    for (int k = 1; k <= 3; ++k) {
        float n = 1.25f * (float)k;               // linspace(0,5,5) step
        float win = 0.42f - 0.5f * cosf(2.0f * PI * n / 5.0f)
                          + 0.08f * cosf(4.0f * PI * n / 5.0f);
        w[k - 1] = (bp[k] / mx) * win;
    }
    return make_float4(w[0], w[1], w[2], 0.0f);
}

// Micro-kernel: 324 filters -> workspace, once per launch (~2 us).
__global__ void build_filters(const float* __restrict__ flow,
                              const float* __restrict__ fband,
                              float4* __restrict__ wtab)
{
    int i = blockIdx.x * blockDim.x + threadIdx.x;   // i = c*NF + f
    if (i < NC * NF) wtab[i] = make_taps(flow[i], fband[i]);
}

// Main conv: block covers 4096 consecutive t for one (b, c).
// Filter loop outermost -> block writes 16 KB contiguous per output row
// before moving to the next row (long write bursts, rows sequential).
__global__ __launch_bounds__(256) void sinc_conv_ws(
    const float* __restrict__ x,
    const float4* __restrict__ wtab,
    float* __restrict__ out)
{
    const int tid  = threadIdx.x;
    const int c    = blockIdx.y;
    const int b    = blockIdx.z;
    const int tile = blockIdx.x * TILE;

    const float4* __restrict__ x4 =
        (const float4*)(x + (size_t)(b * NC + c) * T_IN);

    // Load all input chunks into registers (fully unrolled -> static indices).
    float xa[CHUNKS][8];
    int   ia[CHUNKS];
    bool  ok[CHUNKS];
    #pragma unroll
    for (int ch = 0; ch < CHUNKS; ++ch) {
        int t = tile + ch * 1024 + (tid << 2);
        int i = t >> 2;
        ok[ch] = (t < T_OUT);                 // only t==65532 is invalid
        ia[ch] = i;
        float4 A = x4[i];
        float4 B = x4[ok[ch] ? i + 1 : i];    // clamp avoids OOB on tail
        xa[ch][0] = A.x; xa[ch][1] = A.y; xa[ch][2] = A.z; xa[ch][3] = A.w;
        xa[ch][4] = B.x; xa[ch][5] = B.y; xa[ch][6] = B.z; xa[ch][7] = B.w;
    }

    float* obase = out + (size_t)(b * NC + c) * NF * T_OUT;
    const float4* __restrict__ wt = wtab + c * NF;

    #pragma unroll
    for (int f = 0; f < NF; ++f) {
        const float4 w = wt[f];               // block-uniform broadcast load
        float4* orow = (float4*)(obase + (size_t)f * T_OUT);
        #pragma unroll
        for (int ch = 0; ch < CHUNKS; ++ch) {
            // y[t] = w1*x[t+1] + w2*x[t+2] + w3*x[t+3]
            float4 o;
            o.x = xa[ch][1] * w.x + xa[ch][2] * w.y + xa[ch][3] * w.z;
            o.y = xa[ch][2] * w.x + xa[ch][3] * w.y + xa[ch][4] * w.z;
            o.z = xa[ch][3] * w.x + xa[ch][4] * w.y + xa[ch][5] * w.z;
            o.w = xa[ch][4] * w.x + xa[ch][5] * w.y + xa[ch][6] * w.z;
            if (ok[ch]) orow[ia[ch]] = o;
        }
    }
}

// Fallback (workspace too small): per-block LDS filter build, same conv body.
__global__ __launch_bounds__(256) void sinc_conv_fb(
    const float* __restrict__ x,
    const float* __restrict__ flow,
    const float* __restrict__ fband,
    float* __restrict__ out)
{
    __shared__ float4 sw[NF];
    const int tid  = threadIdx.x;
    const int c    = blockIdx.y;
    const int b    = blockIdx.z;
    const int tile = blockIdx.x * TILE;

    if (tid < NF) sw[tid] = make_taps(flow[c * NF + tid], fband[c * NF + tid]);
    __syncthreads();

    const float4* __restrict__ x4 =
        (const float4*)(x + (size_t)(b * NC + c) * T_IN);

    float xa[CHUNKS][8];
    int   ia[CHUNKS];
    bool  ok[CHUNKS];
    #pragma unroll
    for (int ch = 0; ch < CHUNKS; ++ch) {
        int t = tile + ch * 1024 + (tid << 2);
        int i = t >> 2;
        ok[ch] = (t < T_OUT);
        ia[ch] = i;
        float4 A = x4[i];
        float4 B = x4[ok[ch] ? i + 1 : i];
        xa[ch][0] = A.x; xa[ch][1] = A.y; xa[ch][2] = A.z; xa[ch][3] = A.w;
        xa[ch][4] = B.x; xa[ch][5] = B.y; xa[ch][6] = B.z; xa[ch][7] = B.w;
    }

    float* obase = out + (size_t)(b * NC + c) * NF * T_OUT;

    #pragma unroll
    for (int f = 0; f < NF; ++f) {
        const float4 w = sw[f];
        float4* orow = (float4*)(obase + (size_t)f * T_OUT);
        #pragma unroll
        for (int ch = 0; ch < CHUNKS; ++ch) {
            float4 o;
            o.x = xa[ch][1] * w.x + xa[ch][2] * w.y + xa[ch][3] * w.z;
            o.y = xa[ch][2] * w.x + xa[ch][3] * w.y + xa[ch][4] * w.z;
            o.z = xa[ch][3] * w.x + xa[ch][4] * w.y + xa[ch][5] * w.z;
            o.w = xa[ch][4] * w.x + xa[ch][5] * w.y + xa[ch][6] * w.z;
            if (ok[ch]) orow[ia[ch]] = o;
        }
    }
}

extern "C" void kernel_launch(void* const* d_in, const int* in_sizes, int n_in,
                              void* d_out, int out_size, void* d_ws, size_t ws_size,
                              hipStream_t stream)
{
    const float* x     = (const float*)d_in[0];
    const float* flow  = (const float*)d_in[1];
    const float* fband = (const float*)d_in[2];
    float* out = (float*)d_out;
    (void)in_sizes; (void)n_in; (void)out_size;

    dim3 grid(T_IN / TILE, NC, 8);   // 16 x 27 x 8 = 3456 blocks
    dim3 block(256);

    if (ws_size >= (size_t)(NC * NF) * sizeof(float4)) {
        build_filters<<<1, 384, 0, stream>>>(flow, fband, (float4*)d_ws);
        sinc_conv_ws<<<grid, block, 0, stream>>>(x, (const float4*)d_ws, out);
    } else {
        sinc_conv_fb<<<grid, block, 0, stream>>>(x, flow, fband, out);
    }
}